// Round 3
// baseline (206.228 us; speedup 1.0000x reference)
//
#include <hip/hip_runtime.h>
#include <math.h>

#define B_DIM   64
#define T_DIM   1024
#define E_DIM   512
#define DL_DIM  1024
#define DA_DIM  128
#define CL_DIM  32
#define KW      31

// ws layout (float offsets)
#define WS_WCOMB 0            // 128*31 = 3968
#define WS_BCOMB 3968         // 128
#define WS_PL    4096         // 64*128 = 8192
#define WS_EN    12288        // 64*1024 = 65536
#define WS_PART  77824        // 64*16*512 = 524288 (partial contexts)
#define WS_CNT   602112       // 64 ints (atomic counters), float-indexed
// total < 2.4 MB

// ---------------------------------------------------------------------------
// K1: blocks 0..63: processed_lstm[b][a] = dot(lstm[b], W_lstm[a])
//     block 64:     Wcomb[a][k] = sum_c W_loc[a][c]*conv_w[c][k];
//                   bcomb[a]    = b_loc[a] + sum_c W_loc[a][c]*conv_b[c];
//                   zero the per-b atomic counters used by K3.
// ---------------------------------------------------------------------------
__global__ __launch_bounds__(256) void prep_kernel(
    const float* __restrict__ lstm,    // [B,1,DL]
    const float* __restrict__ W_lstm,  // [DA,DL]
    const float* __restrict__ conv_w,  // [CL,1,KW]
    const float* __restrict__ conv_b,  // [CL]
    const float* __restrict__ W_loc,   // [DA,CL]
    const float* __restrict__ b_loc,   // [DA]
    float* __restrict__ ws) {
  const int blk = blockIdx.x;
  const int tid = threadIdx.x;
  if (blk < B_DIM) {
    const int a = tid >> 1;
    const int h = tid & 1;
    const float4* lv = (const float4*)(lstm + (size_t)blk * DL_DIM + h * (DL_DIM / 2));
    const float4* wv = (const float4*)(W_lstm + (size_t)a * DL_DIM + h * (DL_DIM / 2));
    float acc = 0.f;
#pragma unroll 8
    for (int i = 0; i < DL_DIM / 8; ++i) {
      float4 x = lv[i], y = wv[i];
      acc = fmaf(x.x, y.x, acc);
      acc = fmaf(x.y, y.y, acc);
      acc = fmaf(x.z, y.z, acc);
      acc = fmaf(x.w, y.w, acc);
    }
    acc += __shfl_xor(acc, 1);
    if (h == 0) ws[WS_PL + blk * DA_DIM + a] = acc;
  } else {
    if (tid < DA_DIM) {
      const int a = tid;
      float wl[CL_DIM];
#pragma unroll
      for (int c = 0; c < CL_DIM; ++c) wl[c] = W_loc[a * CL_DIM + c];
      float bc = b_loc[a];
#pragma unroll
      for (int c = 0; c < CL_DIM; ++c) bc = fmaf(wl[c], conv_b[c], bc);
      ws[WS_BCOMB + a] = bc;
      for (int k = 0; k < KW; ++k) {
        float s = 0.f;
#pragma unroll
        for (int c = 0; c < CL_DIM; ++c) s = fmaf(wl[c], conv_w[c * KW + k], s);
        ws[WS_WCOMB + a * KW + k] = s;
      }
    } else if (tid < DA_DIM + B_DIM) {
      ((int*)(ws + WS_CNT))[tid - DA_DIM] = 0;  // zero K3 counters each call
    }
  }
}

// ---------------------------------------------------------------------------
// K2: energies[b][t] = b_e + sum_a W_e[a] * tanh( pl[b][a] + bcomb[a]
//        + sum_k Wcomb[a][k]*awc_pad[b][t+k-15] + peo[b][t][a] )
// grid (16,64): chunks of 64 t. block 256 = 4 waves; each wave 16 t's.
// lane owns a0=2*lane, a1=2*lane+1 (float2 peo loads, Wcomb rows in regs).
// ---------------------------------------------------------------------------
#define TCHUNK 64
__global__ __launch_bounds__(256) void energy_kernel(
    const float* __restrict__ peo,  // [B,T,DA]
    const float* __restrict__ awc,  // [B,T]
    const float* __restrict__ W_e,  // [DA]
    const float* __restrict__ b_e,  // [1]
    float* __restrict__ ws) {
  const int b = blockIdx.y;
  const int t0 = blockIdx.x * TCHUNK;
  const int tid = threadIdx.x;
  const int lane = tid & 63;
  const int wave = tid >> 6;

  __shared__ float s_awc[TCHUNK + KW - 1]; // 94

  for (int i = tid; i < TCHUNK + KW - 1; i += 256) {
    int g = t0 - (KW / 2) + i;
    s_awc[i] = (g >= 0 && g < T_DIM) ? awc[b * T_DIM + g] : 0.f;
  }
  __syncthreads();

  const int a0 = 2 * lane, a1 = 2 * lane + 1;
  float wc0[KW], wc1[KW];
#pragma unroll
  for (int k = 0; k < KW; ++k) {
    wc0[k] = ws[WS_WCOMB + a0 * KW + k];
    wc1[k] = ws[WS_WCOMB + a1 * KW + k];
  }
  const float base0 = ws[WS_PL + b * DA_DIM + a0] + ws[WS_BCOMB + a0];
  const float base1 = ws[WS_PL + b * DA_DIM + a1] + ws[WS_BCOMB + a1];
  const float we0 = W_e[a0], we1 = W_e[a1];
  const float be = b_e[0];

  float keep = 0.f;
#pragma unroll 2
  for (int i = 0; i < TCHUNK / 4; ++i) {
    const int tl = wave * (TCHUNK / 4) + i; // local t
    const int t = t0 + tl;
    const float2 p = *(const float2*)(peo + ((size_t)b * T_DIM + t) * DA_DIM + a0);
    float s0 = base0, s1 = base1;
#pragma unroll
    for (int k = 0; k < KW; ++k) {
      const float aw = s_awc[tl + k];
      s0 = fmaf(aw, wc0[k], s0);
      s1 = fmaf(aw, wc1[k], s1);
    }
    const float x0 = s0 + p.x;
    const float x1 = s1 + p.y;
    // overflow-safe tanh: sign(x)*(1-e)*rcp(1+e), e = exp(-2|x|)
    const float e0 = __expf(-2.f * fabsf(x0));
    const float e1 = __expf(-2.f * fabsf(x1));
    const float th0 = __builtin_copysignf((1.f - e0) * __builtin_amdgcn_rcpf(1.f + e0), x0);
    const float th1 = __builtin_copysignf((1.f - e1) * __builtin_amdgcn_rcpf(1.f + e1), x1);
    float v = fmaf(th0, we0, th1 * we1);
#pragma unroll
    for (int off = 32; off > 0; off >>= 1) v += __shfl_xor(v, off);
    if (lane == i) keep = v; // iteration i's sum parked in lane i
  }
  if (lane < TCHUNK / 4)
    ws[WS_EN + b * T_DIM + t0 + wave * (TCHUNK / 4) + lane] = keep + be;
}

// ---------------------------------------------------------------------------
// K3: softmax (redundant per block, energies are L2-resident) + context
// partial over a CONTIGUOUS t-slab [tc*64, tc*64+64) x all 512 cols.
// Each wave-pair reads whole 2KB rows -> perfectly sequential HBM streams.
// Last block per b (atomic counter) reduces the 16 partials (fixed order =
// deterministic) and writes out[b].
// ---------------------------------------------------------------------------
__global__ __launch_bounds__(256) void context_kernel(
    const float* __restrict__ enc,  // [B,T,E]
    float* __restrict__ ws,
    float* __restrict__ out) {      // [B*E context][B*T weights]
  const int b = blockIdx.y;
  const int tc = blockIdx.x;  // 0..15
  const int tid = threadIdx.x;
  const int lane = tid & 63;
  const int wave = tid >> 6;

  __shared__ float s_w[T_DIM];
  __shared__ float4 s_acc[128];
  __shared__ float s4[4];
  __shared__ int s_last;

  // ---- softmax over b's 1024 energies ----
  const float4 ev = ((const float4*)(ws + WS_EN + (size_t)b * T_DIM))[tid];
  float m = fmaxf(fmaxf(ev.x, ev.y), fmaxf(ev.z, ev.w));
#pragma unroll
  for (int off = 32; off > 0; off >>= 1) m = fmaxf(m, __shfl_xor(m, off));
  if (lane == 0) s4[wave] = m;
  __syncthreads();
  const float M = fmaxf(fmaxf(s4[0], s4[1]), fmaxf(s4[2], s4[3]));
  __syncthreads();
  float4 ex;
  ex.x = __expf(ev.x - M);
  ex.y = __expf(ev.y - M);
  ex.z = __expf(ev.z - M);
  ex.w = __expf(ev.w - M);
  float s = ex.x + ex.y + ex.z + ex.w;
#pragma unroll
  for (int off = 32; off > 0; off >>= 1) s += __shfl_xor(s, off);
  if (lane == 0) s4[wave] = s;
  __syncthreads();
  const float inv = 1.f / (s4[0] + s4[1] + s4[2] + s4[3]);
  float4 wv;
  wv.x = ex.x * inv; wv.y = ex.y * inv; wv.z = ex.z * inv; wv.w = ex.w * inv;
  ((float4*)s_w)[tid] = wv;
  if (tc == 0) ((float4*)(out + B_DIM * E_DIM + (size_t)b * T_DIM))[tid] = wv;
  __syncthreads();

  // ---- contiguous context partial ----
  const int c4 = tid & 127;  // float4 column 0..127 (covers all 512 floats)
  const int rp = tid >> 7;   // row parity
  const int t0 = tc * 64;
  const float4* ep = (const float4*)(enc + ((size_t)b * T_DIM + t0) * E_DIM) + c4;
  float4 acc = make_float4(0.f, 0.f, 0.f, 0.f);
#pragma unroll 8
  for (int i = 0; i < 32; ++i) {
    const int tl = 2 * i + rp;
    const float4 v = ep[(size_t)tl * (E_DIM / 4)];
    const float w = s_w[t0 + tl];
    acc.x = fmaf(w, v.x, acc.x);
    acc.y = fmaf(w, v.y, acc.y);
    acc.z = fmaf(w, v.z, acc.z);
    acc.w = fmaf(w, v.w, acc.w);
  }
  if (rp == 0) s_acc[c4] = acc;
  __syncthreads();
  if (rp == 1) {
    const float4 q = s_acc[c4];
    float4 sum;
    sum.x = acc.x + q.x; sum.y = acc.y + q.y;
    sum.z = acc.z + q.z; sum.w = acc.w + q.w;
    ((float4*)(ws + WS_PART + ((size_t)(b * 16 + tc)) * E_DIM))[c4] = sum;
  }
  __threadfence();  // release partials device-wide
  __syncthreads();
  if (tid == 0) {
    const int old = atomicAdd((int*)(ws + WS_CNT) + b, 1);
    s_last = (old == 15);
  }
  __syncthreads();
  if (s_last) {
    __threadfence();  // acquire other blocks' partials
    if (tid < 128) {
      float4 sum = make_float4(0.f, 0.f, 0.f, 0.f);
#pragma unroll
      for (int j = 0; j < 16; ++j) {
        const float4 q = ((const float4*)(ws + WS_PART + ((size_t)(b * 16 + j)) * E_DIM))[tid];
        sum.x += q.x; sum.y += q.y; sum.z += q.z; sum.w += q.w;
      }
      ((float4*)(out + (size_t)b * E_DIM))[tid] = sum;
    }
  }
}

// ---------------------------------------------------------------------------
extern "C" void kernel_launch(void* const* d_in, const int* in_sizes, int n_in,
                              void* d_out, int out_size, void* d_ws, size_t ws_size,
                              hipStream_t stream) {
  const float* enc    = (const float*)d_in[0];   // [64,1024,512]
  const float* peo    = (const float*)d_in[1];   // [64,1024,128]
  const float* lstm   = (const float*)d_in[2];   // [64,1,1024]
  const float* awc    = (const float*)d_in[3];   // [64,1024]
  const float* W_lstm = (const float*)d_in[4];   // [128,1024]
  const float* conv_w = (const float*)d_in[5];   // [32,1,31]
  const float* conv_b = (const float*)d_in[6];   // [32]
  const float* W_loc  = (const float*)d_in[7];   // [128,32]
  const float* b_loc  = (const float*)d_in[8];   // [128]
  const float* W_e    = (const float*)d_in[9];   // [1,128]
  const float* b_e    = (const float*)d_in[10];  // [1]
  float* out = (float*)d_out;
  float* ws  = (float*)d_ws;

  prep_kernel<<<B_DIM + 1, 256, 0, stream>>>(lstm, W_lstm, conv_w, conv_b,
                                             W_loc, b_loc, ws);
  energy_kernel<<<dim3(T_DIM / TCHUNK, B_DIM), 256, 0, stream>>>(peo, awc, W_e,
                                                                 b_e, ws);
  context_kernel<<<dim3(16, B_DIM), 256, 0, stream>>>(enc, ws, out);
}

// Round 4
// 70.694 us; speedup vs baseline: 2.9172x; 2.9172x over previous
//
#include <hip/hip_runtime.h>
#include <math.h>

#define B_DIM   64
#define T_DIM   1024
#define E_DIM   512
#define DL_DIM  1024
#define DA_DIM  128
#define CL_DIM  32
#define KW      31

// ws layout (float offsets)
#define WS_WCOMB 0            // 128*31 = 3968
#define WS_BCOMB 3968         // 128
#define WS_PL    4096         // 64*128 = 8192
#define WS_EN    12288        // 64*1024 = 65536
#define WS_W     77824        // 64*1024 = 65536 (softmax weights)
#define WS_PART  143360       // 64*16*512 = 524288 (partial contexts)
// total 667648 floats = 2.6 MB

// ---------------------------------------------------------------------------
// K1: blocks 0..63: processed_lstm[b][a] = dot(lstm[b], W_lstm[a])
//     block 64:     Wcomb[a][k] = sum_c W_loc[a][c]*conv_w[c][k];
//                   bcomb[a]    = b_loc[a] + sum_c W_loc[a][c]*conv_b[c]
// ---------------------------------------------------------------------------
__global__ __launch_bounds__(256) void prep_kernel(
    const float* __restrict__ lstm,    // [B,1,DL]
    const float* __restrict__ W_lstm,  // [DA,DL]
    const float* __restrict__ conv_w,  // [CL,1,KW]
    const float* __restrict__ conv_b,  // [CL]
    const float* __restrict__ W_loc,   // [DA,CL]
    const float* __restrict__ b_loc,   // [DA]
    float* __restrict__ ws) {
  const int blk = blockIdx.x;
  const int tid = threadIdx.x;
  if (blk < B_DIM) {
    const int a = tid >> 1;
    const int h = tid & 1;
    const float4* lv = (const float4*)(lstm + (size_t)blk * DL_DIM + h * (DL_DIM / 2));
    const float4* wv = (const float4*)(W_lstm + (size_t)a * DL_DIM + h * (DL_DIM / 2));
    float acc = 0.f;
#pragma unroll 8
    for (int i = 0; i < DL_DIM / 8; ++i) {
      float4 x = lv[i], y = wv[i];
      acc = fmaf(x.x, y.x, acc);
      acc = fmaf(x.y, y.y, acc);
      acc = fmaf(x.z, y.z, acc);
      acc = fmaf(x.w, y.w, acc);
    }
    acc += __shfl_xor(acc, 1);
    if (h == 0) ws[WS_PL + blk * DA_DIM + a] = acc;
  } else if (tid < DA_DIM) {
    const int a = tid;
    float wl[CL_DIM];
#pragma unroll
    for (int c = 0; c < CL_DIM; ++c) wl[c] = W_loc[a * CL_DIM + c];
    float bc = b_loc[a];
#pragma unroll
    for (int c = 0; c < CL_DIM; ++c) bc = fmaf(wl[c], conv_b[c], bc);
    ws[WS_BCOMB + a] = bc;
    for (int k = 0; k < KW; ++k) {
      float s = 0.f;
#pragma unroll
      for (int c = 0; c < CL_DIM; ++c) s = fmaf(wl[c], conv_w[c * KW + k], s);
      ws[WS_WCOMB + a * KW + k] = s;
    }
  }
}

// ---------------------------------------------------------------------------
// K2: energies[b][t] = b_e + sum_a W_e[a] * tanh( pl[b][a] + bcomb[a]
//        + sum_k Wcomb[a][k]*awc_pad[b][t+k-15] + peo[b][t][a] )
// grid (16,64): chunks of 64 t. block 256 = 4 waves; each wave 16 t's.
// ---------------------------------------------------------------------------
#define TCHUNK 64
__global__ __launch_bounds__(256) void energy_kernel(
    const float* __restrict__ peo,  // [B,T,DA]
    const float* __restrict__ awc,  // [B,T]
    const float* __restrict__ W_e,  // [DA]
    const float* __restrict__ b_e,  // [1]
    float* __restrict__ ws) {
  const int b = blockIdx.y;
  const int t0 = blockIdx.x * TCHUNK;
  const int tid = threadIdx.x;
  const int lane = tid & 63;
  const int wave = tid >> 6;

  __shared__ float s_awc[TCHUNK + KW - 1]; // 94

  for (int i = tid; i < TCHUNK + KW - 1; i += 256) {
    int g = t0 - (KW / 2) + i;
    s_awc[i] = (g >= 0 && g < T_DIM) ? awc[b * T_DIM + g] : 0.f;
  }
  __syncthreads();

  const int a0 = 2 * lane, a1 = 2 * lane + 1;
  float wc0[KW], wc1[KW];
#pragma unroll
  for (int k = 0; k < KW; ++k) {
    wc0[k] = ws[WS_WCOMB + a0 * KW + k];
    wc1[k] = ws[WS_WCOMB + a1 * KW + k];
  }
  const float base0 = ws[WS_PL + b * DA_DIM + a0] + ws[WS_BCOMB + a0];
  const float base1 = ws[WS_PL + b * DA_DIM + a1] + ws[WS_BCOMB + a1];
  const float we0 = W_e[a0], we1 = W_e[a1];
  const float be = b_e[0];

  float keep = 0.f;
#pragma unroll 2
  for (int i = 0; i < TCHUNK / 4; ++i) {
    const int tl = wave * (TCHUNK / 4) + i; // local t
    const int t = t0 + tl;
    const float2 p = *(const float2*)(peo + ((size_t)b * T_DIM + t) * DA_DIM + a0);
    float s0 = base0, s1 = base1;
#pragma unroll
    for (int k = 0; k < KW; ++k) {
      const float aw = s_awc[tl + k];
      s0 = fmaf(aw, wc0[k], s0);
      s1 = fmaf(aw, wc1[k], s1);
    }
    const float x0 = s0 + p.x;
    const float x1 = s1 + p.y;
    // overflow-safe tanh: sign(x)*(1-e)*rcp(1+e), e = exp(-2|x|)
    const float e0 = __expf(-2.f * fabsf(x0));
    const float e1 = __expf(-2.f * fabsf(x1));
    const float th0 = __builtin_copysignf((1.f - e0) * __builtin_amdgcn_rcpf(1.f + e0), x0);
    const float th1 = __builtin_copysignf((1.f - e1) * __builtin_amdgcn_rcpf(1.f + e1), x1);
    float v = fmaf(th0, we0, th1 * we1);
#pragma unroll
    for (int off = 32; off > 0; off >>= 1) v += __shfl_xor(v, off);
    if (lane == i) keep = v; // iteration i's sum parked in lane i
  }
  if (lane < TCHUNK / 4)
    ws[WS_EN + b * T_DIM + t0 + wave * (TCHUNK / 4) + lane] = keep + be;
}

// ---------------------------------------------------------------------------
// K2.5: softmax over T per b. grid 64, block 256 (float4 per thread).
// Writes weights to ws (for K3) and to out.
// ---------------------------------------------------------------------------
__global__ __launch_bounds__(256) void softmax_kernel(
    float* __restrict__ ws, float* __restrict__ out) {
  const int b = blockIdx.x;
  const int tid = threadIdx.x;
  const int lane = tid & 63;
  const int wave = tid >> 6;
  __shared__ float s4[4];

  const float4 ev = ((const float4*)(ws + WS_EN + (size_t)b * T_DIM))[tid];
  float m = fmaxf(fmaxf(ev.x, ev.y), fmaxf(ev.z, ev.w));
#pragma unroll
  for (int off = 32; off > 0; off >>= 1) m = fmaxf(m, __shfl_xor(m, off));
  if (lane == 0) s4[wave] = m;
  __syncthreads();
  const float M = fmaxf(fmaxf(s4[0], s4[1]), fmaxf(s4[2], s4[3]));
  __syncthreads();
  float4 ex;
  ex.x = __expf(ev.x - M);
  ex.y = __expf(ev.y - M);
  ex.z = __expf(ev.z - M);
  ex.w = __expf(ev.w - M);
  float s = ex.x + ex.y + ex.z + ex.w;
#pragma unroll
  for (int off = 32; off > 0; off >>= 1) s += __shfl_xor(s, off);
  if (lane == 0) s4[wave] = s;
  __syncthreads();
  const float inv = 1.f / (s4[0] + s4[1] + s4[2] + s4[3]);
  float4 wv;
  wv.x = ex.x * inv; wv.y = ex.y * inv; wv.z = ex.z * inv; wv.w = ex.w * inv;
  ((float4*)(ws + WS_W + (size_t)b * T_DIM))[tid] = wv;
  ((float4*)(out + B_DIM * E_DIM + (size_t)b * T_DIM))[tid] = wv;
}

// ---------------------------------------------------------------------------
// K3: context partials. grid (16,64), block 256 = 4 waves.
// Block (tc,b) owns rows [tc*64, tc*64+64) x all 512 cols = contiguous 128KB.
// Wave w streams rows [w*16, w*16+16) SEQUENTIALLY: per row, lanes read the
// two 1KB halves (lane and 64+lane float4). Pure sequential 32KB per wave.
// No atomics, no fences: partials go to ws; K4 reduces after kernel boundary.
// ---------------------------------------------------------------------------
__global__ __launch_bounds__(256) void context_kernel(
    const float* __restrict__ enc,  // [B,T,E]
    float* __restrict__ ws) {
  const int b = blockIdx.y;
  const int tc = blockIdx.x;  // 0..15
  const int tid = threadIdx.x;
  const int lane = tid & 63;
  const int wave = tid >> 6;
  const int t0 = tc * 64;

  __shared__ float s_w[64];
  __shared__ float4 s_acc[4][128];

  if (tid < 64) s_w[tid] = ws[WS_W + (size_t)b * T_DIM + t0 + tid];
  __syncthreads();

  const float* ep = enc + ((size_t)b * T_DIM + t0 + wave * 16) * E_DIM;
  float4 a0 = make_float4(0.f, 0.f, 0.f, 0.f);
  float4 a1 = make_float4(0.f, 0.f, 0.f, 0.f);
#pragma unroll 4
  for (int r = 0; r < 16; ++r) {
    const float w = s_w[wave * 16 + r];
    const float4 v0 = ((const float4*)(ep + (size_t)r * E_DIM))[lane];
    const float4 v1 = ((const float4*)(ep + (size_t)r * E_DIM))[64 + lane];
    a0.x = fmaf(w, v0.x, a0.x); a0.y = fmaf(w, v0.y, a0.y);
    a0.z = fmaf(w, v0.z, a0.z); a0.w = fmaf(w, v0.w, a0.w);
    a1.x = fmaf(w, v1.x, a1.x); a1.y = fmaf(w, v1.y, a1.y);
    a1.z = fmaf(w, v1.z, a1.z); a1.w = fmaf(w, v1.w, a1.w);
  }
  s_acc[wave][lane] = a0;
  s_acc[wave][64 + lane] = a1;
  __syncthreads();

  if (tid < 128) {
    float4 s = s_acc[0][tid];
#pragma unroll
    for (int w = 1; w < 4; ++w) {
      const float4 q = s_acc[w][tid];
      s.x += q.x; s.y += q.y; s.z += q.z; s.w += q.w;
    }
    ((float4*)(ws + WS_PART + ((size_t)(b * 16 + tc)) * E_DIM))[tid] = s;
  }
}

// ---------------------------------------------------------------------------
// K4: reduce 16 partials per b -> out context. grid 64, block 128.
// ---------------------------------------------------------------------------
__global__ __launch_bounds__(128) void reduce_kernel(
    const float* __restrict__ ws, float* __restrict__ out) {
  const int b = blockIdx.x;
  const int tid = threadIdx.x;  // float4 col 0..127
  float4 s = make_float4(0.f, 0.f, 0.f, 0.f);
#pragma unroll
  for (int j = 0; j < 16; ++j) {
    const float4 q = ((const float4*)(ws + WS_PART + ((size_t)(b * 16 + j)) * E_DIM))[tid];
    s.x += q.x; s.y += q.y; s.z += q.z; s.w += q.w;
  }
  ((float4*)(out + (size_t)b * E_DIM))[tid] = s;
}

// ---------------------------------------------------------------------------
extern "C" void kernel_launch(void* const* d_in, const int* in_sizes, int n_in,
                              void* d_out, int out_size, void* d_ws, size_t ws_size,
                              hipStream_t stream) {
  const float* enc    = (const float*)d_in[0];   // [64,1024,512]
  const float* peo    = (const float*)d_in[1];   // [64,1024,128]
  const float* lstm   = (const float*)d_in[2];   // [64,1,1024]
  const float* awc    = (const float*)d_in[3];   // [64,1024]
  const float* W_lstm = (const float*)d_in[4];   // [128,1024]
  const float* conv_w = (const float*)d_in[5];   // [32,1,31]
  const float* conv_b = (const float*)d_in[6];   // [32]
  const float* W_loc  = (const float*)d_in[7];   // [128,32]
  const float* b_loc  = (const float*)d_in[8];   // [128]
  const float* W_e    = (const float*)d_in[9];   // [1,128]
  const float* b_e    = (const float*)d_in[10];  // [1]
  float* out = (float*)d_out;
  float* ws  = (float*)d_ws;

  prep_kernel<<<B_DIM + 1, 256, 0, stream>>>(lstm, W_lstm, conv_w, conv_b,
                                             W_loc, b_loc, ws);
  energy_kernel<<<dim3(T_DIM / TCHUNK, B_DIM), 256, 0, stream>>>(peo, awc, W_e,
                                                                 b_e, ws);
  softmax_kernel<<<B_DIM, 256, 0, stream>>>(ws, out);
  context_kernel<<<dim3(16, B_DIM), 256, 0, stream>>>(enc, ws);
  reduce_kernel<<<B_DIM, 128, 0, stream>>>(ws, out);
}

// Round 5
// 69.695 us; speedup vs baseline: 2.9590x; 1.0143x over previous
//
#include <hip/hip_runtime.h>
#include <math.h>

#define B_DIM   64
#define T_DIM   1024
#define E_DIM   512
#define DL_DIM  1024
#define DA_DIM  128
#define CL_DIM  32
#define KW      31

// ws layout (float offsets)
#define WS_WCOMB 0            // 128*31 = 3968
#define WS_BCOMB 3968         // 128
#define WS_PL    4096         // 64*128 = 8192
#define WS_EN    12288        // 64*1024 = 65536
#define WS_W     77824        // 64*1024 = 65536 (unused now, kept for layout)
#define WS_PART  143360       // 64*32*512 = 1048576 (partial contexts)
// total ~1.2M floats = 4.8 MB

// ---------------------------------------------------------------------------
// K1: blocks 0..63: processed_lstm[b][a] = dot(lstm[b], W_lstm[a])
//     block 64:     Wcomb[a][k] = sum_c W_loc[a][c]*conv_w[c][k];
//                   bcomb[a]    = b_loc[a] + sum_c W_loc[a][c]*conv_b[c]
// ---------------------------------------------------------------------------
__global__ __launch_bounds__(256) void prep_kernel(
    const float* __restrict__ lstm,    // [B,1,DL]
    const float* __restrict__ W_lstm,  // [DA,DL]
    const float* __restrict__ conv_w,  // [CL,1,KW]
    const float* __restrict__ conv_b,  // [CL]
    const float* __restrict__ W_loc,   // [DA,CL]
    const float* __restrict__ b_loc,   // [DA]
    float* __restrict__ ws) {
  const int blk = blockIdx.x;
  const int tid = threadIdx.x;
  if (blk < B_DIM) {
    const int a = tid >> 1;
    const int h = tid & 1;
    const float4* lv = (const float4*)(lstm + (size_t)blk * DL_DIM + h * (DL_DIM / 2));
    const float4* wv = (const float4*)(W_lstm + (size_t)a * DL_DIM + h * (DL_DIM / 2));
    float acc = 0.f;
#pragma unroll 8
    for (int i = 0; i < DL_DIM / 8; ++i) {
      float4 x = lv[i], y = wv[i];
      acc = fmaf(x.x, y.x, acc);
      acc = fmaf(x.y, y.y, acc);
      acc = fmaf(x.z, y.z, acc);
      acc = fmaf(x.w, y.w, acc);
    }
    acc += __shfl_xor(acc, 1);
    if (h == 0) ws[WS_PL + blk * DA_DIM + a] = acc;
  } else if (tid < DA_DIM) {
    const int a = tid;
    float wl[CL_DIM];
#pragma unroll
    for (int c = 0; c < CL_DIM; ++c) wl[c] = W_loc[a * CL_DIM + c];
    float bc = b_loc[a];
#pragma unroll
    for (int c = 0; c < CL_DIM; ++c) bc = fmaf(wl[c], conv_b[c], bc);
    ws[WS_BCOMB + a] = bc;
    for (int k = 0; k < KW; ++k) {
      float s = 0.f;
#pragma unroll
      for (int c = 0; c < CL_DIM; ++c) s = fmaf(wl[c], conv_w[c * KW + k], s);
      ws[WS_WCOMB + a * KW + k] = s;
    }
  }
}

// ---------------------------------------------------------------------------
// K2: energies[b][t] = b_e + sum_a W_e[a] * tanh( pl[b][a] + bcomb[a]
//        + sum_k Wcomb[a][k]*awc_pad[b][t+k-15] + peo[b][t][a] )
// grid (16,64): chunks of 64 t. block 256 = 4 waves; each wave 16 t's.
// ---------------------------------------------------------------------------
#define TCHUNK 64
__global__ __launch_bounds__(256) void energy_kernel(
    const float* __restrict__ peo,  // [B,T,DA]
    const float* __restrict__ awc,  // [B,T]
    const float* __restrict__ W_e,  // [DA]
    const float* __restrict__ b_e,  // [1]
    float* __restrict__ ws) {
  const int b = blockIdx.y;
  const int t0 = blockIdx.x * TCHUNK;
  const int tid = threadIdx.x;
  const int lane = tid & 63;
  const int wave = tid >> 6;

  __shared__ float s_awc[TCHUNK + KW - 1]; // 94

  for (int i = tid; i < TCHUNK + KW - 1; i += 256) {
    int g = t0 - (KW / 2) + i;
    s_awc[i] = (g >= 0 && g < T_DIM) ? awc[b * T_DIM + g] : 0.f;
  }
  __syncthreads();

  const int a0 = 2 * lane, a1 = 2 * lane + 1;
  float wc0[KW], wc1[KW];
#pragma unroll
  for (int k = 0; k < KW; ++k) {
    wc0[k] = ws[WS_WCOMB + a0 * KW + k];
    wc1[k] = ws[WS_WCOMB + a1 * KW + k];
  }
  const float base0 = ws[WS_PL + b * DA_DIM + a0] + ws[WS_BCOMB + a0];
  const float base1 = ws[WS_PL + b * DA_DIM + a1] + ws[WS_BCOMB + a1];
  const float we0 = W_e[a0], we1 = W_e[a1];
  const float be = b_e[0];

  float keep = 0.f;
#pragma unroll 2
  for (int i = 0; i < TCHUNK / 4; ++i) {
    const int tl = wave * (TCHUNK / 4) + i; // local t
    const int t = t0 + tl;
    const float2 p = *(const float2*)(peo + ((size_t)b * T_DIM + t) * DA_DIM + a0);
    float s0 = base0, s1 = base1;
#pragma unroll
    for (int k = 0; k < KW; ++k) {
      const float aw = s_awc[tl + k];
      s0 = fmaf(aw, wc0[k], s0);
      s1 = fmaf(aw, wc1[k], s1);
    }
    const float x0 = s0 + p.x;
    const float x1 = s1 + p.y;
    // overflow-safe tanh: sign(x)*(1-e)*rcp(1+e), e = exp(-2|x|)
    const float e0 = __expf(-2.f * fabsf(x0));
    const float e1 = __expf(-2.f * fabsf(x1));
    const float th0 = __builtin_copysignf((1.f - e0) * __builtin_amdgcn_rcpf(1.f + e0), x0);
    const float th1 = __builtin_copysignf((1.f - e1) * __builtin_amdgcn_rcpf(1.f + e1), x1);
    float v = fmaf(th0, we0, th1 * we1);
#pragma unroll
    for (int off = 32; off > 0; off >>= 1) v += __shfl_xor(v, off);
    if (lane == i) keep = v; // iteration i's sum parked in lane i
  }
  if (lane < TCHUNK / 4)
    ws[WS_EN + b * T_DIM + t0 + wave * (TCHUNK / 4) + lane] = keep + be;
}

// ---------------------------------------------------------------------------
// K3: fused softmax (redundant per block; energies L2-resident) + context
// partials. grid (32,64), block 256 = 4 waves. Block (tc,b) owns rows
// [tc*32, tc*32+32); wave w streams 8 sequential 2KB rows. 8 blocks/CU for
// 2x MLP vs R4. Partials -> ws, no fences/atomics.
// ---------------------------------------------------------------------------
__global__ __launch_bounds__(256) void context_kernel(
    const float* __restrict__ enc,  // [B,T,E]
    float* __restrict__ ws,
    float* __restrict__ out) {
  const int b = blockIdx.y;
  const int tc = blockIdx.x;  // 0..31
  const int tid = threadIdx.x;
  const int lane = tid & 63;
  const int wave = tid >> 6;

  __shared__ float s_w[T_DIM];
  __shared__ float4 s_acc[4][128];
  __shared__ float s4[4];

  // ---- softmax over b's 1024 energies (redundant per block) ----
  const float4 ev = ((const float4*)(ws + WS_EN + (size_t)b * T_DIM))[tid];
  float m = fmaxf(fmaxf(ev.x, ev.y), fmaxf(ev.z, ev.w));
#pragma unroll
  for (int off = 32; off > 0; off >>= 1) m = fmaxf(m, __shfl_xor(m, off));
  if (lane == 0) s4[wave] = m;
  __syncthreads();
  const float M = fmaxf(fmaxf(s4[0], s4[1]), fmaxf(s4[2], s4[3]));
  __syncthreads();
  float4 ex;
  ex.x = __expf(ev.x - M);
  ex.y = __expf(ev.y - M);
  ex.z = __expf(ev.z - M);
  ex.w = __expf(ev.w - M);
  float s = ex.x + ex.y + ex.z + ex.w;
#pragma unroll
  for (int off = 32; off > 0; off >>= 1) s += __shfl_xor(s, off);
  if (lane == 0) s4[wave] = s;
  __syncthreads();
  const float inv = 1.f / (s4[0] + s4[1] + s4[2] + s4[3]);
  float4 wv;
  wv.x = ex.x * inv; wv.y = ex.y * inv; wv.z = ex.z * inv; wv.w = ex.w * inv;
  ((float4*)s_w)[tid] = wv;
  if (tc == 0) ((float4*)(out + B_DIM * E_DIM + (size_t)b * T_DIM))[tid] = wv;
  __syncthreads();

  // ---- streaming context partial: wave w -> rows tc*32 + w*8 + [0,8) ----
  const int t0 = tc * 32 + wave * 8;
  const float* ep = enc + ((size_t)b * T_DIM + t0) * E_DIM;
  float4 a0 = make_float4(0.f, 0.f, 0.f, 0.f);
  float4 a1 = make_float4(0.f, 0.f, 0.f, 0.f);
#pragma unroll
  for (int r = 0; r < 8; ++r) {
    const float w = s_w[t0 + r];
    const float4 v0 = ((const float4*)(ep + (size_t)r * E_DIM))[lane];
    const float4 v1 = ((const float4*)(ep + (size_t)r * E_DIM))[64 + lane];
    a0.x = fmaf(w, v0.x, a0.x); a0.y = fmaf(w, v0.y, a0.y);
    a0.z = fmaf(w, v0.z, a0.z); a0.w = fmaf(w, v0.w, a0.w);
    a1.x = fmaf(w, v1.x, a1.x); a1.y = fmaf(w, v1.y, a1.y);
    a1.z = fmaf(w, v1.z, a1.z); a1.w = fmaf(w, v1.w, a1.w);
  }
  s_acc[wave][lane] = a0;
  s_acc[wave][64 + lane] = a1;
  __syncthreads();

  if (tid < 128) {
    float4 sum = s_acc[0][tid];
#pragma unroll
    for (int w = 1; w < 4; ++w) {
      const float4 q = s_acc[w][tid];
      sum.x += q.x; sum.y += q.y; sum.z += q.z; sum.w += q.w;
    }
    ((float4*)(ws + WS_PART + ((size_t)(b * 32 + tc)) * E_DIM))[tid] = sum;
  }
}

// ---------------------------------------------------------------------------
// K4: reduce 32 partials per b -> out context. grid 64, block 128.
// ---------------------------------------------------------------------------
__global__ __launch_bounds__(128) void reduce_kernel(
    const float* __restrict__ ws, float* __restrict__ out) {
  const int b = blockIdx.x;
  const int tid = threadIdx.x;  // float4 col 0..127
  float4 s = make_float4(0.f, 0.f, 0.f, 0.f);
#pragma unroll
  for (int j = 0; j < 32; ++j) {
    const float4 q = ((const float4*)(ws + WS_PART + ((size_t)(b * 32 + j)) * E_DIM))[tid];
    s.x += q.x; s.y += q.y; s.z += q.z; s.w += q.w;
  }
  ((float4*)(out + (size_t)b * E_DIM))[tid] = s;
}

// ---------------------------------------------------------------------------
extern "C" void kernel_launch(void* const* d_in, const int* in_sizes, int n_in,
                              void* d_out, int out_size, void* d_ws, size_t ws_size,
                              hipStream_t stream) {
  const float* enc    = (const float*)d_in[0];   // [64,1024,512]
  const float* peo    = (const float*)d_in[1];   // [64,1024,128]
  const float* lstm   = (const float*)d_in[2];   // [64,1,1024]
  const float* awc    = (const float*)d_in[3];   // [64,1024]
  const float* W_lstm = (const float*)d_in[4];   // [128,1024]
  const float* conv_w = (const float*)d_in[5];   // [32,1,31]
  const float* conv_b = (const float*)d_in[6];   // [32]
  const float* W_loc  = (const float*)d_in[7];   // [128,32]
  const float* b_loc  = (const float*)d_in[8];   // [128]
  const float* W_e    = (const float*)d_in[9];   // [1,128]
  const float* b_e    = (const float*)d_in[10];  // [1]
  float* out = (float*)d_out;
  float* ws  = (float*)d_ws;

  prep_kernel<<<B_DIM + 1, 256, 0, stream>>>(lstm, W_lstm, conv_w, conv_b,
                                             W_loc, b_loc, ws);
  energy_kernel<<<dim3(T_DIM / TCHUNK, B_DIM), 256, 0, stream>>>(peo, awc, W_e,
                                                                 b_e, ws);
  context_kernel<<<dim3(32, B_DIM), 256, 0, stream>>>(enc, ws, out);
  reduce_kernel<<<B_DIM, 128, 0, stream>>>(ws, out);
}

// Round 6
// 68.360 us; speedup vs baseline: 3.0168x; 1.0195x over previous
//
#include <hip/hip_runtime.h>
#include <math.h>

#define B_DIM   64
#define T_DIM   1024
#define E_DIM   512
#define DL_DIM  1024
#define DA_DIM  128
#define CL_DIM  32
#define KW      31
#define KWP     32   // padded conv width (k=31 is zero)

// ws layout (float offsets)
#define WS_WCOMB 0            // 128*32 = 4096 (stride-32 padded rows)
#define WS_BCOMB 4096         // 128
#define WS_PL    4224         // 64*128 = 8192
#define WS_EN    16384        // 64*1024 = 65536
#define WS_PART  81920        // 64*32*512 = 1048576 (partial contexts)
// total 1130496 floats = 4.5 MB

// ---------------------------------------------------------------------------
// K1: blocks 0..63: processed_lstm[b][a] = dot(lstm[b], W_lstm[a])
//     block 64:     Wcomb[a][k] = sum_c W_loc[a][c]*conv_w[c][k] (stride 32,
//                   k=31 zeroed); bcomb[a] = b_loc[a] + sum_c W_loc[a][c]*conv_b[c]
// ---------------------------------------------------------------------------
__global__ __launch_bounds__(256) void prep_kernel(
    const float* __restrict__ lstm,    // [B,1,DL]
    const float* __restrict__ W_lstm,  // [DA,DL]
    const float* __restrict__ conv_w,  // [CL,1,KW]
    const float* __restrict__ conv_b,  // [CL]
    const float* __restrict__ W_loc,   // [DA,CL]
    const float* __restrict__ b_loc,   // [DA]
    float* __restrict__ ws) {
  const int blk = blockIdx.x;
  const int tid = threadIdx.x;
  if (blk < B_DIM) {
    const int a = tid >> 1;
    const int h = tid & 1;
    const float4* lv = (const float4*)(lstm + (size_t)blk * DL_DIM + h * (DL_DIM / 2));
    const float4* wv = (const float4*)(W_lstm + (size_t)a * DL_DIM + h * (DL_DIM / 2));
    float acc = 0.f;
#pragma unroll 8
    for (int i = 0; i < DL_DIM / 8; ++i) {
      float4 x = lv[i], y = wv[i];
      acc = fmaf(x.x, y.x, acc);
      acc = fmaf(x.y, y.y, acc);
      acc = fmaf(x.z, y.z, acc);
      acc = fmaf(x.w, y.w, acc);
    }
    acc += __shfl_xor(acc, 1);
    if (h == 0) ws[WS_PL + blk * DA_DIM + a] = acc;
  } else if (tid < DA_DIM) {
    const int a = tid;
    float wl[CL_DIM];
#pragma unroll
    for (int c = 0; c < CL_DIM; ++c) wl[c] = W_loc[a * CL_DIM + c];
    float bc = b_loc[a];
#pragma unroll
    for (int c = 0; c < CL_DIM; ++c) bc = fmaf(wl[c], conv_b[c], bc);
    ws[WS_BCOMB + a] = bc;
    for (int k = 0; k < KWP; ++k) {
      float s = 0.f;
      if (k < KW) {
#pragma unroll
        for (int c = 0; c < CL_DIM; ++c) s = fmaf(wl[c], conv_w[c * KW + k], s);
      }
      ws[WS_WCOMB + a * KWP + k] = s;
    }
  }
}

// ---------------------------------------------------------------------------
// K2: energies[b][t] = b_e + sum_a W_e[a] * tanh( pl[b][a] + bcomb[a]
//        + sum_k Wcomb[a][k]*awc_pad[b][t+k-15] + peo[b][t][a] )
// grid (16,64), block 256 = 4 waves; wave w owns t in [t0+16w, t0+16w+16).
// Lane owns a0=2*lane, a1=2*lane+1. awc window and Wcomb rows live in
// REGISTERS (no per-FMA LDS reads); per-t partials v[16] are reduced via one
// LDS transpose (pad 68) + 2 shfl_xor instead of a 6-deep butterfly per t.
// ---------------------------------------------------------------------------
#define TCHUNK 64
__global__ __launch_bounds__(256, 2) void energy_kernel(
    const float* __restrict__ peo,  // [B,T,DA]
    const float* __restrict__ awc,  // [B,T]
    const float* __restrict__ W_e,  // [DA]
    const float* __restrict__ b_e,  // [1]
    float* __restrict__ ws) {
  const int b = blockIdx.y;
  const int t0 = blockIdx.x * TCHUNK;
  const int tid = threadIdx.x;
  const int lane = tid & 63;
  const int wave = tid >> 6;

  __shared__ float s_awc[96];          // window [t0-15, t0+80], pad zeros
  __shared__ float s_red[4][16][68];   // per-wave transpose buffer (pad 68)

  for (int i = tid; i < 96; i += 256) {
    const int g = t0 - (KW / 2) + i;
    s_awc[i] = (i < TCHUNK + KW - 1 && g >= 0 && g < T_DIM) ? awc[b * T_DIM + g] : 0.f;
  }
  __syncthreads();

  // ---- register copies: awc window (48) and Wcomb rows (2x32) ----
  float aw[48];
  {
    const float4* awp = (const float4*)(s_awc + wave * 16);
#pragma unroll
    for (int j = 0; j < 12; ++j) {
      const float4 q = awp[j];
      aw[4 * j + 0] = q.x; aw[4 * j + 1] = q.y;
      aw[4 * j + 2] = q.z; aw[4 * j + 3] = q.w;
    }
  }
  const int a0 = 2 * lane, a1 = 2 * lane + 1;
  float wc0[KWP], wc1[KWP];
  {
    const float4* w0p = (const float4*)(ws + WS_WCOMB + a0 * KWP);
    const float4* w1p = (const float4*)(ws + WS_WCOMB + a1 * KWP);
#pragma unroll
    for (int j = 0; j < 8; ++j) {
      const float4 q0 = w0p[j], q1 = w1p[j];
      wc0[4 * j + 0] = q0.x; wc0[4 * j + 1] = q0.y;
      wc0[4 * j + 2] = q0.z; wc0[4 * j + 3] = q0.w;
      wc1[4 * j + 0] = q1.x; wc1[4 * j + 1] = q1.y;
      wc1[4 * j + 2] = q1.z; wc1[4 * j + 3] = q1.w;
    }
  }
  const float base0 = ws[WS_PL + b * DA_DIM + a0] + ws[WS_BCOMB + a0];
  const float base1 = ws[WS_PL + b * DA_DIM + a1] + ws[WS_BCOMB + a1];
  const float we0 = W_e[a0], we1 = W_e[a1];
  const float be = b_e[0];

  // ---- main loop: 16 t's, all operands in registers ----
  float v[16];
#pragma unroll
  for (int i = 0; i < 16; ++i) {
    const int t = t0 + wave * 16 + i;
    const float2 p = *(const float2*)(peo + ((size_t)b * T_DIM + t) * DA_DIM + a0);
    float s0 = base0, s1 = base1;
#pragma unroll
    for (int k = 0; k < KWP; ++k) {
      s0 = fmaf(aw[i + k], wc0[k], s0);
      s1 = fmaf(aw[i + k], wc1[k], s1);
    }
    const float x0 = s0 + p.x;
    const float x1 = s1 + p.y;
    // overflow-safe tanh: sign(x)*(1-e)*rcp(1+e), e = exp(-2|x|)
    const float e0 = __expf(-2.f * fabsf(x0));
    const float e1 = __expf(-2.f * fabsf(x1));
    const float th0 = __builtin_copysignf((1.f - e0) * __builtin_amdgcn_rcpf(1.f + e0), x0);
    const float th1 = __builtin_copysignf((1.f - e1) * __builtin_amdgcn_rcpf(1.f + e1), x1);
    v[i] = fmaf(th0, we0, th1 * we1);
  }

  // ---- transpose reduce: 64 partials per t -> 1 energy, 16 t's at once ----
#pragma unroll
  for (int i = 0; i < 16; ++i) s_red[wave][i][lane] = v[i];
  __syncthreads();
  {
    const int t = lane >> 2;   // 0..15
    const int sub = lane & 3;  // 0..3
    const float4* rp = (const float4*)(&s_red[wave][t][sub * 16]);
    float4 q0 = rp[0], q1 = rp[1], q2 = rp[2], q3 = rp[3];
    float s = ((q0.x + q0.y) + (q0.z + q0.w)) + ((q1.x + q1.y) + (q1.z + q1.w))
            + ((q2.x + q2.y) + (q2.z + q2.w)) + ((q3.x + q3.y) + (q3.z + q3.w));
    s += __shfl_xor(s, 1);
    s += __shfl_xor(s, 2);
    if (sub == 0)
      ws[WS_EN + b * T_DIM + t0 + wave * 16 + t] = s + be;
  }
}

// ---------------------------------------------------------------------------
// K3: fused softmax (redundant per block; energies L2-resident) + context
// partials. grid (32,64), block 256 = 4 waves. Block (tc,b) owns rows
// [tc*32, tc*32+32); wave w streams 8 sequential 2KB rows.
// ---------------------------------------------------------------------------
__global__ __launch_bounds__(256) void context_kernel(
    const float* __restrict__ enc,  // [B,T,E]
    float* __restrict__ ws,
    float* __restrict__ out) {
  const int b = blockIdx.y;
  const int tc = blockIdx.x;  // 0..31
  const int tid = threadIdx.x;
  const int lane = tid & 63;
  const int wave = tid >> 6;

  __shared__ float s_w[T_DIM];
  __shared__ float4 s_acc[4][128];
  __shared__ float s4[4];

  // ---- softmax over b's 1024 energies (redundant per block) ----
  const float4 ev = ((const float4*)(ws + WS_EN + (size_t)b * T_DIM))[tid];
  float m = fmaxf(fmaxf(ev.x, ev.y), fmaxf(ev.z, ev.w));
#pragma unroll
  for (int off = 32; off > 0; off >>= 1) m = fmaxf(m, __shfl_xor(m, off));
  if (lane == 0) s4[wave] = m;
  __syncthreads();
  const float M = fmaxf(fmaxf(s4[0], s4[1]), fmaxf(s4[2], s4[3]));
  __syncthreads();
  float4 ex;
  ex.x = __expf(ev.x - M);
  ex.y = __expf(ev.y - M);
  ex.z = __expf(ev.z - M);
  ex.w = __expf(ev.w - M);
  float s = ex.x + ex.y + ex.z + ex.w;
#pragma unroll
  for (int off = 32; off > 0; off >>= 1) s += __shfl_xor(s, off);
  if (lane == 0) s4[wave] = s;
  __syncthreads();
  const float inv = 1.f / (s4[0] + s4[1] + s4[2] + s4[3]);
  float4 wv;
  wv.x = ex.x * inv; wv.y = ex.y * inv; wv.z = ex.z * inv; wv.w = ex.w * inv;
  ((float4*)s_w)[tid] = wv;
  if (tc == 0) ((float4*)(out + B_DIM * E_DIM + (size_t)b * T_DIM))[tid] = wv;
  __syncthreads();

  // ---- streaming context partial: wave w -> rows tc*32 + w*8 + [0,8) ----
  const int t0 = tc * 32 + wave * 8;
  const float* ep = enc + ((size_t)b * T_DIM + t0) * E_DIM;
  float4 a0 = make_float4(0.f, 0.f, 0.f, 0.f);
  float4 a1 = make_float4(0.f, 0.f, 0.f, 0.f);
#pragma unroll
  for (int r = 0; r < 8; ++r) {
    const float w = s_w[t0 + r];
    const float4 v0 = ((const float4*)(ep + (size_t)r * E_DIM))[lane];
    const float4 v1 = ((const float4*)(ep + (size_t)r * E_DIM))[64 + lane];
    a0.x = fmaf(w, v0.x, a0.x); a0.y = fmaf(w, v0.y, a0.y);
    a0.z = fmaf(w, v0.z, a0.z); a0.w = fmaf(w, v0.w, a0.w);
    a1.x = fmaf(w, v1.x, a1.x); a1.y = fmaf(w, v1.y, a1.y);
    a1.z = fmaf(w, v1.z, a1.z); a1.w = fmaf(w, v1.w, a1.w);
  }
  s_acc[wave][lane] = a0;
  s_acc[wave][64 + lane] = a1;
  __syncthreads();

  if (tid < 128) {
    float4 sum = s_acc[0][tid];
#pragma unroll
    for (int w = 1; w < 4; ++w) {
      const float4 q = s_acc[w][tid];
      sum.x += q.x; sum.y += q.y; sum.z += q.z; sum.w += q.w;
    }
    ((float4*)(ws + WS_PART + ((size_t)(b * 32 + tc)) * E_DIM))[tid] = sum;
  }
}

// ---------------------------------------------------------------------------
// K4: reduce 32 partials per b -> out context. grid 64, block 128.
// ---------------------------------------------------------------------------
__global__ __launch_bounds__(128) void reduce_kernel(
    const float* __restrict__ ws, float* __restrict__ out) {
  const int b = blockIdx.x;
  const int tid = threadIdx.x;  // float4 col 0..127
  float4 s = make_float4(0.f, 0.f, 0.f, 0.f);
#pragma unroll
  for (int j = 0; j < 32; ++j) {
    const float4 q = ((const float4*)(ws + WS_PART + ((size_t)(b * 32 + j)) * E_DIM))[tid];
    s.x += q.x; s.y += q.y; s.z += q.z; s.w += q.w;
  }
  ((float4*)(out + (size_t)b * E_DIM))[tid] = s;
}

// ---------------------------------------------------------------------------
extern "C" void kernel_launch(void* const* d_in, const int* in_sizes, int n_in,
                              void* d_out, int out_size, void* d_ws, size_t ws_size,
                              hipStream_t stream) {
  const float* enc    = (const float*)d_in[0];   // [64,1024,512]
  const float* peo    = (const float*)d_in[1];   // [64,1024,128]
  const float* lstm   = (const float*)d_in[2];   // [64,1,1024]
  const float* awc    = (const float*)d_in[3];   // [64,1024]
  const float* W_lstm = (const float*)d_in[4];   // [128,1024]
  const float* conv_w = (const float*)d_in[5];   // [32,1,31]
  const float* conv_b = (const float*)d_in[6];   // [32]
  const float* W_loc  = (const float*)d_in[7];   // [128,32]
  const float* b_loc  = (const float*)d_in[8];   // [128]
  const float* W_e    = (const float*)d_in[9];   // [1,128]
  const float* b_e    = (const float*)d_in[10];  // [1]
  float* out = (float*)d_out;
  float* ws  = (float*)d_ws;

  prep_kernel<<<B_DIM + 1, 256, 0, stream>>>(lstm, W_lstm, conv_w, conv_b,
                                             W_loc, b_loc, ws);
  energy_kernel<<<dim3(T_DIM / TCHUNK, B_DIM), 256, 0, stream>>>(peo, awc, W_e,
                                                                 b_e, ws);
  context_kernel<<<dim3(32, B_DIM), 256, 0, stream>>>(enc, ws, out);
  reduce_kernel<<<B_DIM, 128, 0, stream>>>(ws, out);
}

// Round 7
// 66.026 us; speedup vs baseline: 3.1234x; 1.0353x over previous
//
#include <hip/hip_runtime.h>
#include <math.h>

#define B_DIM   64
#define T_DIM   1024
#define E_DIM   512
#define DL_DIM  1024
#define DA_DIM  128
#define CL_DIM  32
#define KW      31
#define KWP     32   // padded conv width (k=31 is zero)

// ws layout (float offsets)
#define WS_WCOMB 0            // 128*32 = 4096 (stride-32 padded rows)
#define WS_BCOMB 4096         // 128
#define WS_PL    4224         // 64*128 = 8192
#define WS_EN    16384        // 64*1024 = 65536
// total 81920 floats = 328 KB

// ---------------------------------------------------------------------------
// K1: blocks 0..63: processed_lstm[b][a] = dot(lstm[b], W_lstm[a])
//     block 64:     Wcomb[a][k] = sum_c W_loc[a][c]*conv_w[c][k] (stride 32,
//                   k=31 zeroed); bcomb[a] = b_loc[a] + sum_c W_loc[a][c]*conv_b[c]
// ---------------------------------------------------------------------------
__global__ __launch_bounds__(256) void prep_kernel(
    const float* __restrict__ lstm,    // [B,1,DL]
    const float* __restrict__ W_lstm,  // [DA,DL]
    const float* __restrict__ conv_w,  // [CL,1,KW]
    const float* __restrict__ conv_b,  // [CL]
    const float* __restrict__ W_loc,   // [DA,CL]
    const float* __restrict__ b_loc,   // [DA]
    float* __restrict__ ws) {
  const int blk = blockIdx.x;
  const int tid = threadIdx.x;
  if (blk < B_DIM) {
    const int a = tid >> 1;
    const int h = tid & 1;
    const float4* lv = (const float4*)(lstm + (size_t)blk * DL_DIM + h * (DL_DIM / 2));
    const float4* wv = (const float4*)(W_lstm + (size_t)a * DL_DIM + h * (DL_DIM / 2));
    float acc = 0.f;
#pragma unroll 8
    for (int i = 0; i < DL_DIM / 8; ++i) {
      float4 x = lv[i], y = wv[i];
      acc = fmaf(x.x, y.x, acc);
      acc = fmaf(x.y, y.y, acc);
      acc = fmaf(x.z, y.z, acc);
      acc = fmaf(x.w, y.w, acc);
    }
    acc += __shfl_xor(acc, 1);
    if (h == 0) ws[WS_PL + blk * DA_DIM + a] = acc;
  } else if (tid < DA_DIM) {
    const int a = tid;
    float wl[CL_DIM];
#pragma unroll
    for (int c = 0; c < CL_DIM; ++c) wl[c] = W_loc[a * CL_DIM + c];
    float bc = b_loc[a];
#pragma unroll
    for (int c = 0; c < CL_DIM; ++c) bc = fmaf(wl[c], conv_b[c], bc);
    ws[WS_BCOMB + a] = bc;
    for (int k = 0; k < KWP; ++k) {
      float s = 0.f;
      if (k < KW) {
#pragma unroll
        for (int c = 0; c < CL_DIM; ++c) s = fmaf(wl[c], conv_w[c * KW + k], s);
      }
      ws[WS_WCOMB + a * KWP + k] = s;
    }
  }
}

// ---------------------------------------------------------------------------
// K2: energies[b][t] = b_e + sum_a W_e[a] * tanh( pl[b][a] + bcomb[a]
//        + sum_k Wcomb[a][k]*awc_pad[b][t+k-15] + peo[b][t][a] )
// grid (16,64), block 256 = 4 waves; wave w owns t in [t0+16w, t0+16w+16).
// All FMA operands register-resident; one LDS transpose reduce at the end.
// ---------------------------------------------------------------------------
#define TCHUNK 64
__global__ __launch_bounds__(256, 2) void energy_kernel(
    const float* __restrict__ peo,  // [B,T,DA]
    const float* __restrict__ awc,  // [B,T]
    const float* __restrict__ W_e,  // [DA]
    const float* __restrict__ b_e,  // [1]
    float* __restrict__ ws) {
  const int b = blockIdx.y;
  const int t0 = blockIdx.x * TCHUNK;
  const int tid = threadIdx.x;
  const int lane = tid & 63;
  const int wave = tid >> 6;

  __shared__ float s_awc[96];          // window [t0-15, t0+80], pad zeros
  __shared__ float s_red[4][16][68];   // per-wave transpose buffer (pad 68)

  for (int i = tid; i < 96; i += 256) {
    const int g = t0 - (KW / 2) + i;
    s_awc[i] = (i < TCHUNK + KW - 1 && g >= 0 && g < T_DIM) ? awc[b * T_DIM + g] : 0.f;
  }
  __syncthreads();

  // ---- register copies: awc window (48) and Wcomb rows (2x32) ----
  float aw[48];
  {
    const float4* awp = (const float4*)(s_awc + wave * 16);
#pragma unroll
    for (int j = 0; j < 12; ++j) {
      const float4 q = awp[j];
      aw[4 * j + 0] = q.x; aw[4 * j + 1] = q.y;
      aw[4 * j + 2] = q.z; aw[4 * j + 3] = q.w;
    }
  }
  const int a0 = 2 * lane, a1 = 2 * lane + 1;
  float wc0[KWP], wc1[KWP];
  {
    const float4* w0p = (const float4*)(ws + WS_WCOMB + a0 * KWP);
    const float4* w1p = (const float4*)(ws + WS_WCOMB + a1 * KWP);
#pragma unroll
    for (int j = 0; j < 8; ++j) {
      const float4 q0 = w0p[j], q1 = w1p[j];
      wc0[4 * j + 0] = q0.x; wc0[4 * j + 1] = q0.y;
      wc0[4 * j + 2] = q0.z; wc0[4 * j + 3] = q0.w;
      wc1[4 * j + 0] = q1.x; wc1[4 * j + 1] = q1.y;
      wc1[4 * j + 2] = q1.z; wc1[4 * j + 3] = q1.w;
    }
  }
  const float base0 = ws[WS_PL + b * DA_DIM + a0] + ws[WS_BCOMB + a0];
  const float base1 = ws[WS_PL + b * DA_DIM + a1] + ws[WS_BCOMB + a1];
  const float we0 = W_e[a0], we1 = W_e[a1];
  const float be = b_e[0];

  // ---- main loop: 16 t's, all operands in registers ----
  float v[16];
#pragma unroll
  for (int i = 0; i < 16; ++i) {
    const int t = t0 + wave * 16 + i;
    const float2 p = *(const float2*)(peo + ((size_t)b * T_DIM + t) * DA_DIM + a0);
    float s0 = base0, s1 = base1;
#pragma unroll
    for (int k = 0; k < KWP; ++k) {
      s0 = fmaf(aw[i + k], wc0[k], s0);
      s1 = fmaf(aw[i + k], wc1[k], s1);
    }
    const float x0 = s0 + p.x;
    const float x1 = s1 + p.y;
    // overflow-safe tanh: sign(x)*(1-e)*rcp(1+e), e = exp(-2|x|)
    const float e0 = __expf(-2.f * fabsf(x0));
    const float e1 = __expf(-2.f * fabsf(x1));
    const float th0 = __builtin_copysignf((1.f - e0) * __builtin_amdgcn_rcpf(1.f + e0), x0);
    const float th1 = __builtin_copysignf((1.f - e1) * __builtin_amdgcn_rcpf(1.f + e1), x1);
    v[i] = fmaf(th0, we0, th1 * we1);
  }

  // ---- transpose reduce: 64 partials per t -> 1 energy, 16 t's at once ----
#pragma unroll
  for (int i = 0; i < 16; ++i) s_red[wave][i][lane] = v[i];
  __syncthreads();
  {
    const int t = lane >> 2;   // 0..15
    const int sub = lane & 3;  // 0..3
    const float4* rp = (const float4*)(&s_red[wave][t][sub * 16]);
    float4 q0 = rp[0], q1 = rp[1], q2 = rp[2], q3 = rp[3];
    float s = ((q0.x + q0.y) + (q0.z + q0.w)) + ((q1.x + q1.y) + (q1.z + q1.w))
            + ((q2.x + q2.y) + (q2.z + q2.w)) + ((q3.x + q3.y) + (q3.z + q3.w));
    s += __shfl_xor(s, 1);
    s += __shfl_xor(s, 2);
    if (sub == 0)
      ws[WS_EN + b * T_DIM + t0 + wave * 16 + t] = s + be;
  }
}

// ---------------------------------------------------------------------------
// K3: fused softmax (redundant per block; energies L2-resident) + context
// over a 32-column chunk x ALL 1024 t -> writes out DIRECTLY (no partials,
// no reduce kernel). grid (16,64), block 256. Each block's 32 cols are
// disjoint, so no cross-block communication of any kind.
// ---------------------------------------------------------------------------
__global__ __launch_bounds__(256) void context_kernel(
    const float* __restrict__ enc,  // [B,T,E]
    const float* __restrict__ ws,
    float* __restrict__ out) {      // [B*E context][B*T weights]
  const int b = blockIdx.y;
  const int ec = blockIdx.x;  // 0..15 (columns ec*32 .. ec*32+32)
  const int tid = threadIdx.x;
  const int lane = tid & 63;
  const int wave = tid >> 6;

  __shared__ float s_w[T_DIM];
  __shared__ float4 s_acc[32][8];
  __shared__ float s4[4];

  // ---- softmax over b's 1024 energies (redundant per block) ----
  const float4 ev = ((const float4*)(ws + WS_EN + (size_t)b * T_DIM))[tid];
  float m = fmaxf(fmaxf(ev.x, ev.y), fmaxf(ev.z, ev.w));
#pragma unroll
  for (int off = 32; off > 0; off >>= 1) m = fmaxf(m, __shfl_xor(m, off));
  if (lane == 0) s4[wave] = m;
  __syncthreads();
  const float M = fmaxf(fmaxf(s4[0], s4[1]), fmaxf(s4[2], s4[3]));
  __syncthreads();
  float4 ex;
  ex.x = __expf(ev.x - M);
  ex.y = __expf(ev.y - M);
  ex.z = __expf(ev.z - M);
  ex.w = __expf(ev.w - M);
  float s = ex.x + ex.y + ex.z + ex.w;
#pragma unroll
  for (int off = 32; off > 0; off >>= 1) s += __shfl_xor(s, off);
  if (lane == 0) s4[wave] = s;
  __syncthreads();
  const float inv = 1.f / (s4[0] + s4[1] + s4[2] + s4[3]);
  float4 wv;
  wv.x = ex.x * inv; wv.y = ex.y * inv; wv.z = ex.z * inv; wv.w = ex.w * inv;
  ((float4*)s_w)[tid] = wv;
  if (ec == 0) ((float4*)(out + B_DIM * E_DIM + (size_t)b * T_DIM))[tid] = wv;
  __syncthreads();

  // ---- context: acc[col] = sum_t w[t]*enc[b][t][col], cols = ec*32+[0,32) ----
  const int c = tid & 7;    // float4 col within chunk
  const int r = tid >> 3;   // 0..31, t stride 32
  const float4* ep = (const float4*)(enc + (size_t)b * T_DIM * E_DIM) + ec * 8 + c;
  float4 acc = make_float4(0.f, 0.f, 0.f, 0.f);
#pragma unroll 8
  for (int t = r; t < T_DIM; t += 32) {
    const float4 v = ep[(size_t)t * (E_DIM / 4)];
    const float w = s_w[t];
    acc.x = fmaf(w, v.x, acc.x);
    acc.y = fmaf(w, v.y, acc.y);
    acc.z = fmaf(w, v.z, acc.z);
    acc.w = fmaf(w, v.w, acc.w);
  }
  s_acc[r][c] = acc;
  __syncthreads();
  if (tid < 64) {
    const int cc = tid & 7;
    const int i = tid >> 3;  // 0..7
    float4 sv = s_acc[i][cc];
#pragma unroll
    for (int j = 8; j < 32; j += 8) {
      const float4 q = s_acc[i + j][cc];
      sv.x += q.x; sv.y += q.y; sv.z += q.z; sv.w += q.w;
    }
    s_acc[i][cc] = sv;
  }
  __syncthreads();
  if (tid < 8) {
    float4 sv = s_acc[0][tid];
#pragma unroll
    for (int i = 1; i < 8; ++i) {
      const float4 q = s_acc[i][tid];
      sv.x += q.x; sv.y += q.y; sv.z += q.z; sv.w += q.w;
    }
    ((float4*)(out + (size_t)b * E_DIM))[ec * 8 + tid] = sv;
  }
}

// ---------------------------------------------------------------------------
extern "C" void kernel_launch(void* const* d_in, const int* in_sizes, int n_in,
                              void* d_out, int out_size, void* d_ws, size_t ws_size,
                              hipStream_t stream) {
  const float* enc    = (const float*)d_in[0];   // [64,1024,512]
  const float* peo    = (const float*)d_in[1];   // [64,1024,128]
  const float* lstm   = (const float*)d_in[2];   // [64,1,1024]
  const float* awc    = (const float*)d_in[3];   // [64,1024]
  const float* W_lstm = (const float*)d_in[4];   // [128,1024]
  const float* conv_w = (const float*)d_in[5];   // [32,1,31]
  const float* conv_b = (const float*)d_in[6];   // [32]
  const float* W_loc  = (const float*)d_in[7];   // [128,32]
  const float* b_loc  = (const float*)d_in[8];   // [128]
  const float* W_e    = (const float*)d_in[9];   // [1,128]
  const float* b_e    = (const float*)d_in[10];  // [1]
  float* out = (float*)d_out;
  float* ws  = (float*)d_ws;

  prep_kernel<<<B_DIM + 1, 256, 0, stream>>>(lstm, W_lstm, conv_w, conv_b,
                                             W_loc, b_loc, ws);
  energy_kernel<<<dim3(T_DIM / TCHUNK, B_DIM), 256, 0, stream>>>(peo, awc, W_e,
                                                                 b_e, ws);
  context_kernel<<<dim3(16, B_DIM), 256, 0, stream>>>(enc, ws, out);
}

// Round 8
// 53.728 us; speedup vs baseline: 3.8383x; 1.2289x over previous
//
#include <hip/hip_runtime.h>
#include <math.h>

#define B_DIM   64
#define T_DIM   1024
#define E_DIM   512
#define DL_DIM  1024
#define DA_DIM  128
#define CL_DIM  32
#define KW      31
#define KWP     32   // padded conv width (k=31 is zero)

// ws layout (float offsets)
#define WS_WCOMB 0            // 128*32 = 4096 (stride-32 padded rows)
#define WS_BCOMB 4096         // 128
#define WS_PL    4224         // 64*128 = 8192
#define WS_EN    16384        // 64*1024 = 65536
// total 81920 floats = 328 KB

// ---------------------------------------------------------------------------
// K1: blocks 0..255: processed_lstm. Block (b,q): rows a in [q*32, q*32+32).
//     8 threads per row, each a 128-elem sub-dot, 3-step shfl reduce.
//     Per block: 128 KB W_lstm + 4 KB lstm. 4x CUs, 1/4 chain vs R7.
//     block 256: Wcomb[a][k] = sum_c W_loc[a][c]*conv_w[c][k] (stride 32,
//     k=31 zeroed); bcomb[a] = b_loc[a] + sum_c W_loc[a][c]*conv_b[c]
// ---------------------------------------------------------------------------
__global__ __launch_bounds__(256) void prep_kernel(
    const float* __restrict__ lstm,    // [B,1,DL]
    const float* __restrict__ W_lstm,  // [DA,DL]
    const float* __restrict__ conv_w,  // [CL,1,KW]
    const float* __restrict__ conv_b,  // [CL]
    const float* __restrict__ W_loc,   // [DA,CL]
    const float* __restrict__ b_loc,   // [DA]
    float* __restrict__ ws) {
  const int blk = blockIdx.x;
  const int tid = threadIdx.x;
  if (blk < 4 * B_DIM) {
    const int b = blk >> 2;
    const int q = blk & 3;
    const int a = q * 32 + (tid >> 3);  // 32 rows per block
    const int h = tid & 7;              // 8 sub-dots per row
    const float4* lv = (const float4*)(lstm + (size_t)b * DL_DIM + h * 128);
    const float4* wv = (const float4*)(W_lstm + (size_t)a * DL_DIM + h * 128);
    float acc = 0.f;
#pragma unroll 8
    for (int i = 0; i < 32; ++i) {
      const float4 x = lv[i], y = wv[i];
      acc = fmaf(x.x, y.x, acc);
      acc = fmaf(x.y, y.y, acc);
      acc = fmaf(x.z, y.z, acc);
      acc = fmaf(x.w, y.w, acc);
    }
    acc += __shfl_xor(acc, 1);
    acc += __shfl_xor(acc, 2);
    acc += __shfl_xor(acc, 4);
    if (h == 0) ws[WS_PL + b * DA_DIM + a] = acc;
  } else if (tid < DA_DIM) {
    const int a = tid;
    float wl[CL_DIM];
#pragma unroll
    for (int c = 0; c < CL_DIM; ++c) wl[c] = W_loc[a * CL_DIM + c];
    float bc = b_loc[a];
#pragma unroll
    for (int c = 0; c < CL_DIM; ++c) bc = fmaf(wl[c], conv_b[c], bc);
    ws[WS_BCOMB + a] = bc;
    for (int k = 0; k < KWP; ++k) {
      float s = 0.f;
      if (k < KW) {
#pragma unroll
        for (int c = 0; c < CL_DIM; ++c) s = fmaf(wl[c], conv_w[c * KW + k], s);
      }
      ws[WS_WCOMB + a * KWP + k] = s;
    }
  }
}

// ---------------------------------------------------------------------------
// K2: energies[b][t] = b_e + sum_a W_e[a] * tanh( pl[b][a] + bcomb[a]
//        + sum_k Wcomb[a][k]*awc_pad[b][t+k-15] + peo[b][t][a] )
// grid (16,64), block 256 = 4 waves; wave w owns t in [t0+16w, t0+16w+16).
// All FMA operands register-resident; one LDS transpose reduce at the end.
// ---------------------------------------------------------------------------
#define TCHUNK 64
__global__ __launch_bounds__(256, 2) void energy_kernel(
    const float* __restrict__ peo,  // [B,T,DA]
    const float* __restrict__ awc,  // [B,T]
    const float* __restrict__ W_e,  // [DA]
    const float* __restrict__ b_e,  // [1]
    float* __restrict__ ws) {
  const int b = blockIdx.y;
  const int t0 = blockIdx.x * TCHUNK;
  const int tid = threadIdx.x;
  const int lane = tid & 63;
  const int wave = tid >> 6;

  __shared__ float s_awc[96];          // window [t0-15, t0+80], pad zeros
  __shared__ float s_red[4][16][68];   // per-wave transpose buffer (pad 68)

  for (int i = tid; i < 96; i += 256) {
    const int g = t0 - (KW / 2) + i;
    s_awc[i] = (i < TCHUNK + KW - 1 && g >= 0 && g < T_DIM) ? awc[b * T_DIM + g] : 0.f;
  }
  __syncthreads();

  // ---- register copies: awc window (48) and Wcomb rows (2x32) ----
  float aw[48];
  {
    const float4* awp = (const float4*)(s_awc + wave * 16);
#pragma unroll
    for (int j = 0; j < 12; ++j) {
      const float4 q = awp[j];
      aw[4 * j + 0] = q.x; aw[4 * j + 1] = q.y;
      aw[4 * j + 2] = q.z; aw[4 * j + 3] = q.w;
    }
  }
  const int a0 = 2 * lane, a1 = 2 * lane + 1;
  float wc0[KWP], wc1[KWP];
  {
    const float4* w0p = (const float4*)(ws + WS_WCOMB + a0 * KWP);
    const float4* w1p = (const float4*)(ws + WS_WCOMB + a1 * KWP);
#pragma unroll
    for (int j = 0; j < 8; ++j) {
      const float4 q0 = w0p[j], q1 = w1p[j];
      wc0[4 * j + 0] = q0.x; wc0[4 * j + 1] = q0.y;
      wc0[4 * j + 2] = q0.z; wc0[4 * j + 3] = q0.w;
      wc1[4 * j + 0] = q1.x; wc1[4 * j + 1] = q1.y;
      wc1[4 * j + 2] = q1.z; wc1[4 * j + 3] = q1.w;
    }
  }
  const float base0 = ws[WS_PL + b * DA_DIM + a0] + ws[WS_BCOMB + a0];
  const float base1 = ws[WS_PL + b * DA_DIM + a1] + ws[WS_BCOMB + a1];
  const float we0 = W_e[a0], we1 = W_e[a1];
  const float be = b_e[0];

  // ---- main loop: 16 t's, all operands in registers ----
  float v[16];
#pragma unroll
  for (int i = 0; i < 16; ++i) {
    const int t = t0 + wave * 16 + i;
    const float2 p = *(const float2*)(peo + ((size_t)b * T_DIM + t) * DA_DIM + a0);
    float s0 = base0, s1 = base1;
#pragma unroll
    for (int k = 0; k < KWP; ++k) {
      s0 = fmaf(aw[i + k], wc0[k], s0);
      s1 = fmaf(aw[i + k], wc1[k], s1);
    }
    const float x0 = s0 + p.x;
    const float x1 = s1 + p.y;
    // overflow-safe tanh: sign(x)*(1-e)*rcp(1+e), e = exp(-2|x|)
    const float e0 = __expf(-2.f * fabsf(x0));
    const float e1 = __expf(-2.f * fabsf(x1));
    const float th0 = __builtin_copysignf((1.f - e0) * __builtin_amdgcn_rcpf(1.f + e0), x0);
    const float th1 = __builtin_copysignf((1.f - e1) * __builtin_amdgcn_rcpf(1.f + e1), x1);
    v[i] = fmaf(th0, we0, th1 * we1);
  }

  // ---- transpose reduce: 64 partials per t -> 1 energy, 16 t's at once ----
#pragma unroll
  for (int i = 0; i < 16; ++i) s_red[wave][i][lane] = v[i];
  __syncthreads();
  {
    const int t = lane >> 2;   // 0..15
    const int sub = lane & 3;  // 0..3
    const float4* rp = (const float4*)(&s_red[wave][t][sub * 16]);
    float4 q0 = rp[0], q1 = rp[1], q2 = rp[2], q3 = rp[3];
    float s = ((q0.x + q0.y) + (q0.z + q0.w)) + ((q1.x + q1.y) + (q1.z + q1.w))
            + ((q2.x + q2.y) + (q2.z + q2.w)) + ((q3.x + q3.y) + (q3.z + q3.w));
    s += __shfl_xor(s, 1);
    s += __shfl_xor(s, 2);
    if (sub == 0)
      ws[WS_EN + b * T_DIM + t0 + wave * 16 + t] = s + be;
  }
}

// ---------------------------------------------------------------------------
// K3: fused softmax (redundant per block; energies L2-resident) + context
// over a 32-column chunk x ALL 1024 t -> writes out DIRECTLY. grid (16,64),
// block 256. Disjoint columns per block -> no cross-block communication.
// ---------------------------------------------------------------------------
__global__ __launch_bounds__(256) void context_kernel(
    const float* __restrict__ enc,  // [B,T,E]
    const float* __restrict__ ws,
    float* __restrict__ out) {      // [B*E context][B*T weights]
  const int b = blockIdx.y;
  const int ec = blockIdx.x;  // 0..15 (columns ec*32 .. ec*32+32)
  const int tid = threadIdx.x;
  const int lane = tid & 63;
  const int wave = tid >> 6;

  __shared__ float s_w[T_DIM];
  __shared__ float4 s_acc[32][8];
  __shared__ float s4[4];

  // ---- softmax over b's 1024 energies (redundant per block) ----
  const float4 ev = ((const float4*)(ws + WS_EN + (size_t)b * T_DIM))[tid];
  float m = fmaxf(fmaxf(ev.x, ev.y), fmaxf(ev.z, ev.w));
#pragma unroll
  for (int off = 32; off > 0; off >>= 1) m = fmaxf(m, __shfl_xor(m, off));
  if (lane == 0) s4[wave] = m;
  __syncthreads();
  const float M = fmaxf(fmaxf(s4[0], s4[1]), fmaxf(s4[2], s4[3]));
  __syncthreads();
  float4 ex;
  ex.x = __expf(ev.x - M);
  ex.y = __expf(ev.y - M);
  ex.z = __expf(ev.z - M);
  ex.w = __expf(ev.w - M);
  float s = ex.x + ex.y + ex.z + ex.w;
#pragma unroll
  for (int off = 32; off > 0; off >>= 1) s += __shfl_xor(s, off);
  if (lane == 0) s4[wave] = s;
  __syncthreads();
  const float inv = 1.f / (s4[0] + s4[1] + s4[2] + s4[3]);
  float4 wv;
  wv.x = ex.x * inv; wv.y = ex.y * inv; wv.z = ex.z * inv; wv.w = ex.w * inv;
  ((float4*)s_w)[tid] = wv;
  if (ec == 0) ((float4*)(out + B_DIM * E_DIM + (size_t)b * T_DIM))[tid] = wv;
  __syncthreads();

  // ---- context: acc[col] = sum_t w[t]*enc[b][t][col], cols = ec*32+[0,32) ----
  const int c = tid & 7;    // float4 col within chunk
  const int r = tid >> 3;   // 0..31, t stride 32
  const float4* ep = (const float4*)(enc + (size_t)b * T_DIM * E_DIM) + ec * 8 + c;
  float4 acc = make_float4(0.f, 0.f, 0.f, 0.f);
#pragma unroll 8
  for (int t = r; t < T_DIM; t += 32) {
    const float4 v = ep[(size_t)t * (E_DIM / 4)];
    const float w = s_w[t];
    acc.x = fmaf(w, v.x, acc.x);
    acc.y = fmaf(w, v.y, acc.y);
    acc.z = fmaf(w, v.z, acc.z);
    acc.w = fmaf(w, v.w, acc.w);
  }
  s_acc[r][c] = acc;
  __syncthreads();
  if (tid < 64) {
    const int cc = tid & 7;
    const int i = tid >> 3;  // 0..7
    float4 sv = s_acc[i][cc];
#pragma unroll
    for (int j = 8; j < 32; j += 8) {
      const float4 q = s_acc[i + j][cc];
      sv.x += q.x; sv.y += q.y; sv.z += q.z; sv.w += q.w;
    }
    s_acc[i][cc] = sv;
  }
  __syncthreads();
  if (tid < 8) {
    float4 sv = s_acc[0][tid];
#pragma unroll
    for (int i = 1; i < 8; ++i) {
      const float4 q = s_acc[i][tid];
      sv.x += q.x; sv.y += q.y; sv.z += q.z; sv.w += q.w;
    }
    ((float4*)(out + (size_t)b * E_DIM))[ec * 8 + tid] = sv;
  }
}

// ---------------------------------------------------------------------------
extern "C" void kernel_launch(void* const* d_in, const int* in_sizes, int n_in,
                              void* d_out, int out_size, void* d_ws, size_t ws_size,
                              hipStream_t stream) {
  const float* enc    = (const float*)d_in[0];   // [64,1024,512]
  const float* peo    = (const float*)d_in[1];   // [64,1024,128]
  const float* lstm   = (const float*)d_in[2];   // [64,1,1024]
  const float* awc    = (const float*)d_in[3];   // [64,1024]
  const float* W_lstm = (const float*)d_in[4];   // [128,1024]
  const float* conv_w = (const float*)d_in[5];   // [32,1,31]
  const float* conv_b = (const float*)d_in[6];   // [32]
  const float* W_loc  = (const float*)d_in[7];   // [128,32]
  const float* b_loc  = (const float*)d_in[8];   // [128]
  const float* W_e    = (const float*)d_in[9];   // [1,128]
  const float* b_e    = (const float*)d_in[10];  // [1]
  float* out = (float*)d_out;
  float* ws  = (float*)d_ws;

  prep_kernel<<<4 * B_DIM + 1, 256, 0, stream>>>(lstm, W_lstm, conv_w, conv_b,
                                                 W_loc, b_loc, ws);
  energy_kernel<<<dim3(T_DIM / TCHUNK, B_DIM), 256, 0, stream>>>(peo, awc, W_e,
                                                                 b_e, ws);
  context_kernel<<<dim3(16, B_DIM), 256, 0, stream>>>(enc, ws, out);
}